// Round 2
// baseline (449.223 us; speedup 1.0000x reference)
//
#include <hip/hip_runtime.h>
#include <hip/hip_bf16.h>
#include <stdint.h>

#define B_    64
#define S_    2048
#define ENC_  512
#define ATTN_ 256

typedef __bf16 bf16;
typedef bf16  bf16x8 __attribute__((ext_vector_type(8)));
typedef float f32x4  __attribute__((ext_vector_type(4)));

__device__ __forceinline__ float fexp2(float x) {
#if __has_builtin(__builtin_amdgcn_exp2f)
    return __builtin_amdgcn_exp2f(x);
#else
    return exp2f(x);
#endif
}
__device__ __forceinline__ float frcp(float x) {
#if __has_builtin(__builtin_amdgcn_rcpf)
    return __builtin_amdgcn_rcpf(x);
#else
    return 1.0f / x;
#endif
}
// tanh(x) = 1 - 2/(e^{2x}+1); overflow-safe (exp2->inf => 1, ->0 => -1)
__device__ __forceinline__ float fast_tanh(float x) {
    float e = fexp2(x * 2.8853900817779268f);
    return 1.0f - 2.0f * frcp(e + 1.0f);
}

__device__ __forceinline__ void async_copy16(const void* g, void* l) {
#if __has_builtin(__builtin_amdgcn_global_load_lds)
    __builtin_amdgcn_global_load_lds(
        (__attribute__((address_space(1))) void*)(g),
        (__attribute__((address_space(3))) void*)(l), 16, 0, 0);
#else
    *(uint4*)l = *(const uint4*)g;
#endif
}

// ---------------- setup: WT transpose->bf16 (blocks 0..511) + dec_proj (512..575)
// dec_proj blocks also zero ctx (needed for atomicAdd epilogue in k_ctx).
__global__ __launch_bounds__(256) void k_setup(const float* __restrict__ W_enc,
                                               const float* __restrict__ dec_state,
                                               const float* __restrict__ W_dec,
                                               bf16* __restrict__ WT,
                                               float* __restrict__ dp,
                                               float* __restrict__ ctx) {
    int blk = blockIdx.x;
    if (blk < 512) {
        int idx = blk * 256 + threadIdx.x;      // 0..131071
        int n = idx >> 9;                        // /512
        int k = idx & 511;
        WT[idx] = (bf16)W_enc[k * ATTN_ + n];    // coalesced writes
    } else {
        int b = blk - 512;
        int a = threadIdx.x;
        *(float2*)(ctx + b * 512 + a * 2) = make_float2(0.f, 0.f);
        const float* ds = dec_state + b * 512;
        float acc = 0.f;
#pragma unroll 8
        for (int d = 0; d < 512; ++d)
            acc += ds[d] * W_dec[d * ATTN_ + a];
        dp[b * ATTN_ + a] = acc;
    }
}

__device__ __forceinline__ void stage_b(const bf16* __restrict__ WT, bf16* bsbuf,
                                        int ks, int bcol4, int bslot, int tid) {
#pragma unroll
    for (int r = 0; r < 4; ++r) {
        int c = r * 64 + bcol4;
        int g = bslot ^ ((c + (c >> 2)) & 3);     // fetch swizzled chunk
        async_copy16(WT + (size_t)c * 512 + ks * 32 + g * 8,
                     bsbuf + r * 2048 + tid * 8);
    }
}

__device__ __forceinline__ void load_a4(const float* s, float4& f0, float4& f1,
                                        float4& f2, float4& f3) {
    f0 = *(const float4*)(s);
    f1 = *(const float4*)(s + 4);
    f2 = *(const float4*)(s + 8);
    f3 = *(const float4*)(s + 12);
}

__device__ __forceinline__ void cvt_store(bf16* dst, float4 f0, float4 f1,
                                          float4 f2, float4 f3) {
    bf16x8 lo, hi;
    lo[0]=(bf16)f0.x; lo[1]=(bf16)f0.y; lo[2]=(bf16)f0.z; lo[3]=(bf16)f0.w;
    lo[4]=(bf16)f1.x; lo[5]=(bf16)f1.y; lo[6]=(bf16)f1.z; lo[7]=(bf16)f1.w;
    hi[0]=(bf16)f2.x; hi[1]=(bf16)f2.y; hi[2]=(bf16)f2.z; hi[3]=(bf16)f2.w;
    hi[4]=(bf16)f3.x; hi[5]=(bf16)f3.y; hi[6]=(bf16)f3.z; hi[7]=(bf16)f3.w;
    *(bf16x8*)(dst)     = lo;
    *(bf16x8*)(dst + 8) = hi;
}

// ---------------- scores: GEMM(M=131072,K=512,N=256) + tanh.v epilogue ----
// v3: A-prefetch DEPTH 2 in registers. A(ks+2) is issued during step ks and
// consumed (cvt->LDS) at the end of step ks+1 — ~2 K-steps of compute cover
// the ~900cy HBM latency instead of ~300cy. Static even/odd reg rotation.
__global__ __launch_bounds__(256, 2) void k_scores(
    const float* __restrict__ enc,    // [131072][512]
    const bf16*  __restrict__ WT,     // [256][512] (n-major)
    const float* __restrict__ dp,     // [64][256]
    const float* __restrict__ v,      // [256]
    float* __restrict__ out_scores)   // [131072]
{
    __shared__ __align__(16) bf16 As[2][128 * 40];   // 2 x 10.0 KB, padded rows
    __shared__ __align__(16) bf16 Bs[2][256 * 32];   // 2 x 16.0 KB, swizzled chunks
    __shared__ float partial[4][64];

    const int tid  = threadIdx.x;
    const int wave = tid >> 6;
    const int lane = tid & 63;
    const int l15  = lane & 15;
    const int q    = lane >> 4;
    const int m0   = blockIdx.x * 128;
    const int b    = blockIdx.x >> 4;            // 16 blocks per batch

    const int mrow0 = (wave >> 1) * 64;
    const int ncol0 = (wave & 1) * 128;

    const f32x4 zero4 = {0.f, 0.f, 0.f, 0.f};
    f32x4 acc[4][8];
#pragma unroll
    for (int mt = 0; mt < 4; ++mt)
#pragma unroll
        for (int nt = 0; nt < 8; ++nt)
            acc[mt][nt] = zero4;

    // A staging: thread t -> row t>>1, k-half (t&1)*16 floats
    const int arow = tid >> 1;
    const int akc  = tid & 1;
    const float* ag = enc + (size_t)(m0 + arow) * 512 + akc * 16;
    const int aoff = arow * 40 + akc * 16;

    // B staging: round r -> col c = r*64 + (t>>2), chunk slot t&3
    const int bcol4 = tid >> 2;
    const int bslot = tid & 3;

    // A prefetch registers: X and Y buffers (static rotation)
    float4 xa0, xa1, xa2, xa3;   // X
    float4 ya0, ya1, ya2, ya3;   // Y

    // ---- prologue: issue A(0)->X, A(1)->Y, stage B(0); publish As[0] ----
    load_a4(ag,      xa0, xa1, xa2, xa3);
    load_a4(ag + 32, ya0, ya1, ya2, ya3);
    stage_b(WT, Bs[0], 0, bcol4, bslot, tid);
    cvt_store(&As[0][aoff], xa0, xa1, xa2, xa3);
    __syncthreads();

#pragma unroll
    for (int ks = 0; ks < 16; ++ks) {
        const int cur = ks & 1;
        const bf16* Asc = As[cur];
        const bf16* Bsc = Bs[cur];

        // ---- fragments (current buffer) ----
        bf16x8 af[4];
#pragma unroll
        for (int mt = 0; mt < 4; ++mt) {
            int row = mrow0 + mt * 16 + l15;
            af[mt] = *(const bf16x8*)(Asc + row * 40 + q * 8);
        }
        bf16x8 bfr[8];
#pragma unroll
        for (int nt = 0; nt < 8; ++nt) {
            int col = ncol0 + nt * 16 + l15;
            int p = q ^ ((col + (col >> 2)) & 3);
            bfr[nt] = *(const bf16x8*)(Bsc + col * 32 + p * 8);
        }

        // ---- issue next-tile loads BEFORE compute ----
        if (ks < 15) stage_b(WT, Bs[cur ^ 1], ks + 1, bcol4, bslot, tid);
        if (ks < 14) {
            const float* s = ag + (ks + 2) * 32;
            if ((ks & 1) == 0) load_a4(s, xa0, xa1, xa2, xa3);   // even: refill X
            else               load_a4(s, ya0, ya1, ya2, ya3);   // odd:  refill Y
        }

#pragma unroll
        for (int mt = 0; mt < 4; ++mt)
#pragma unroll
            for (int nt = 0; nt < 8; ++nt)
                acc[mt][nt] = __builtin_amdgcn_mfma_f32_16x16x32_bf16(af[mt], bfr[nt], acc[mt][nt], 0, 0, 0);

        // ---- convert + write A(ks+1) (issued two steps ago) ----
        if (ks < 15) {
            bf16* dst = &As[cur ^ 1][aoff];
            if ((ks & 1) == 0) cvt_store(dst, ya0, ya1, ya2, ya3);  // even consumes Y
            else               cvt_store(dst, xa0, xa1, xa2, xa3);  // odd  consumes X
        }
        __syncthreads();   // single barrier: publishes next buffer, retires reads
    }

    // ---- epilogue: scores[row] = sum_col tanh(C + dp[col]) * v[col] ----
    float dpv[8], vv[8];
#pragma unroll
    for (int nt = 0; nt < 8; ++nt) {
        int col = ncol0 + nt * 16 + l15;
        dpv[nt] = dp[b * 256 + col];
        vv[nt]  = v[col];
    }
#pragma unroll
    for (int mt = 0; mt < 4; ++mt) {
#pragma unroll
        for (int r = 0; r < 4; ++r) {
            float s = 0.f;
#pragma unroll
            for (int nt = 0; nt < 8; ++nt)
                s += fast_tanh(acc[mt][nt][r] + dpv[nt]) * vv[nt];
            s += __shfl_xor(s, 1, 16);
            s += __shfl_xor(s, 2, 16);
            s += __shfl_xor(s, 4, 16);
            s += __shfl_xor(s, 8, 16);
            if (l15 == 0)
                partial[wave][mt * 16 + q * 4 + r] = s;
        }
    }
    __syncthreads();
    if (tid < 128) {
        int mw   = tid >> 6;
        int rloc = tid & 63;
        out_scores[m0 + mw * 64 + rloc] =
            partial[mw * 2][rloc] + partial[mw * 2 + 1][rloc];
    }
}

// ---------------- fused softmax + context + reduce ------------------------
// v3: grid = 64 b x 32 slabs (64 rows) = 2048 blocks -> 8 blocks/CU resident.
// Softmax stats via wave shuffles (2 barriers, not 16). First enc load group
// is peeled AHEAD of the softmax so 8x16B/thread are in flight covering it.
__global__ __launch_bounds__(256) void k_ctx(const float* __restrict__ enc,
                                             const float* __restrict__ scores,
                                             float* __restrict__ attn,
                                             float* __restrict__ ctx) {
    __shared__ float redm[4], reds[4];
    __shared__ float wlds[64];
    __shared__ f32x4 vred[128];

    const int tid  = threadIdx.x;
    const int wave = tid >> 6;
    const int lane = tid & 63;
    const int b    = blockIdx.x >> 5;
    const int slab = blockIdx.x & 31;
    const float* sc = scores + b * 2048;

    const int eq = tid & 127;                 // e = eq*4 (float4)
    const int sr = tid >> 7;                  // 0/1 — wave-uniform
    const float* eb = enc + ((size_t)b * 2048 + slab * 64) * 512;

    // ---- peel g=0: issue 8 independent loads before the softmax ----
    f32x4 ev0[8];
#pragma unroll
    for (int j = 0; j < 8; ++j)
        ev0[j] = *(const f32x4*)(eb + (size_t)(sr * 8 + j) * 512 + eq * 4);

    // ---- softmax stats over the batch's 2048 scores (shuffle trees) ----
    float x[8];
    float mx = -1e30f;
#pragma unroll
    for (int i = 0; i < 8; ++i) { x[i] = sc[tid + 256 * i]; mx = fmaxf(mx, x[i]); }
#pragma unroll
    for (int d = 1; d < 64; d <<= 1) mx = fmaxf(mx, __shfl_xor(mx, d));
    if (lane == 0) redm[wave] = mx;
    __syncthreads();
    mx = fmaxf(fmaxf(redm[0], redm[1]), fmaxf(redm[2], redm[3]));

    float e[8];
    float lsum = 0.f;
#pragma unroll
    for (int i = 0; i < 8; ++i) { e[i] = fexp2((x[i] - mx) * 1.4426950408889634f); lsum += e[i]; }
#pragma unroll
    for (int d = 1; d < 64; d <<= 1) lsum += __shfl_xor(lsum, d);
    if (lane == 0) reds[wave] = lsum;
    __syncthreads();
    float inv = 1.0f / (reds[0] + reds[1] + reds[2] + reds[3]);

    // ---- weights: own slab only (global + LDS copy) ----
#pragma unroll
    for (int i = 0; i < 8; ++i) {
        int idx = tid + 256 * i;
        int r   = idx - slab * 64;
        if ((unsigned)r < 64u) {
            float w = e[i] * inv;
            attn[b * 2048 + idx] = w;
            wlds[r] = w;
        }
    }
    __syncthreads();

    // ---- context partial over 64 rows ----
    f32x4 acc = {0.f, 0.f, 0.f, 0.f};
#pragma unroll
    for (int j = 0; j < 8; ++j) acc += ev0[j] * wlds[sr * 8 + j];

    for (int g = 1; g < 4; ++g) {
        const int sbase = g * 16 + sr * 8;
        f32x4 ev[8];
        float wv[8];
#pragma unroll
        for (int j = 0; j < 8; ++j) {
            ev[j] = *(const f32x4*)(eb + (size_t)(sbase + j) * 512 + eq * 4);
            wv[j] = wlds[sbase + j];
        }
#pragma unroll
        for (int j = 0; j < 8; ++j) acc += ev[j] * wv[j];
    }
    if (sr) vred[eq] = acc;
    __syncthreads();
    if (!sr) {
        acc += vred[eq];
        float* cp = ctx + b * 512 + eq * 4;
        atomicAdd(cp + 0, acc[0]);
        atomicAdd(cp + 1, acc[1]);
        atomicAdd(cp + 2, acc[2]);
        atomicAdd(cp + 3, acc[3]);
    }
}

extern "C" void kernel_launch(void* const* d_in, const int* in_sizes, int n_in,
                              void* d_out, int out_size, void* d_ws, size_t ws_size,
                              hipStream_t stream) {
    const float* enc       = (const float*)d_in[0];
    const float* dec_state = (const float*)d_in[1];
    const float* W_enc     = (const float*)d_in[2];
    const float* W_dec     = (const float*)d_in[3];
    const float* v         = (const float*)d_in[4];

    float* ctx  = (float*)d_out;                 // [64,512]
    float* attn = (float*)d_out + 64 * 512;      // [64,2048] weights

    // workspace: WT bf16 256KB | dp fp32 64KB | scores fp32 512KB
    char*  ws     = (char*)d_ws;
    bf16*  WT     = (bf16*)ws;
    float* dp     = (float*)(ws + 256 * 1024);
    float* scores = (float*)(ws + 256 * 1024 + 64 * 1024);

    k_setup <<<576, 256, 0, stream>>>(W_enc, dec_state, W_dec, WT, dp, ctx);
    k_scores<<<1024, 256, 0, stream>>>(enc, WT, dp, v, scores);
    k_ctx   <<<2048, 256, 0, stream>>>(enc, scores, attn, ctx);
}

// Round 3
// 437.563 us; speedup vs baseline: 1.0266x; 1.0266x over previous
//
#include <hip/hip_runtime.h>
#include <hip/hip_bf16.h>
#include <stdint.h>

#define B_    64
#define S_    2048
#define ENC_  512
#define ATTN_ 256

typedef __bf16 bf16;
typedef bf16  bf16x8 __attribute__((ext_vector_type(8)));
typedef float f32x4  __attribute__((ext_vector_type(4)));

__device__ __forceinline__ float fexp2(float x) {
#if __has_builtin(__builtin_amdgcn_exp2f)
    return __builtin_amdgcn_exp2f(x);
#else
    return exp2f(x);
#endif
}
__device__ __forceinline__ float frcp(float x) {
#if __has_builtin(__builtin_amdgcn_rcpf)
    return __builtin_amdgcn_rcpf(x);
#else
    return 1.0f / x;
#endif
}
// tanh(x) = 1 - 2/(e^{2x}+1); overflow-safe (exp2->inf => 1, ->0 => -1)
__device__ __forceinline__ float fast_tanh(float x) {
    float e = fexp2(x * 2.8853900817779268f);
    return 1.0f - 2.0f * frcp(e + 1.0f);
}

__device__ __forceinline__ void async_copy16(const void* g, void* l) {
#if __has_builtin(__builtin_amdgcn_global_load_lds)
    __builtin_amdgcn_global_load_lds(
        (__attribute__((address_space(1))) void*)(g),
        (__attribute__((address_space(3))) void*)(l), 16, 0, 0);
#else
    *(uint4*)l = *(const uint4*)g;
#endif
}

// ---------------- setup: WT transpose->bf16 (blocks 0..511) + dec_proj (512..575)
// dec_proj blocks also zero ctx_acc/esum (atomicAdd targets in k_scores_ctx).
__global__ __launch_bounds__(256) void k_setup(const float* __restrict__ W_enc,
                                               const float* __restrict__ dec_state,
                                               const float* __restrict__ W_dec,
                                               bf16* __restrict__ WT,
                                               float* __restrict__ dp,
                                               float* __restrict__ ctx_acc,
                                               float* __restrict__ esum) {
    int blk = blockIdx.x;
    if (blk < 512) {
        int idx = blk * 256 + threadIdx.x;      // 0..131071
        int n = idx >> 9;                        // /512
        int k = idx & 511;
        WT[idx] = (bf16)W_enc[k * ATTN_ + n];    // coalesced writes
    } else {
        int b = blk - 512;
        int a = threadIdx.x;
        *(float2*)(ctx_acc + b * 512 + a * 2) = make_float2(0.f, 0.f);
        if (a == 0) esum[b] = 0.f;
        const float* ds = dec_state + b * 512;
        float acc = 0.f;
#pragma unroll 8
        for (int d = 0; d < 512; ++d)
            acc += ds[d] * W_dec[d * ATTN_ + a];
        dp[b * ATTN_ + a] = acc;
    }
}

__device__ __forceinline__ void stage_b(const bf16* __restrict__ WT, bf16* bsbuf,
                                        int ks, int bcol4, int bslot, int tid) {
#pragma unroll
    for (int r = 0; r < 4; ++r) {
        int c = r * 64 + bcol4;
        int g = bslot ^ ((c + (c >> 2)) & 3);     // fetch swizzled chunk
        async_copy16(WT + (size_t)c * 512 + ks * 32 + g * 8,
                     bsbuf + r * 2048 + tid * 8);
    }
}

__device__ __forceinline__ void load_a4(const float* s, float4& f0, float4& f1,
                                        float4& f2, float4& f3) {
    f0 = *(const float4*)(s);
    f1 = *(const float4*)(s + 4);
    f2 = *(const float4*)(s + 8);
    f3 = *(const float4*)(s + 12);
}

__device__ __forceinline__ void cvt_store(bf16* dst, float4 f0, float4 f1,
                                          float4 f2, float4 f3) {
    bf16x8 lo, hi;
    lo[0]=(bf16)f0.x; lo[1]=(bf16)f0.y; lo[2]=(bf16)f0.z; lo[3]=(bf16)f0.w;
    lo[4]=(bf16)f1.x; lo[5]=(bf16)f1.y; lo[6]=(bf16)f1.z; lo[7]=(bf16)f1.w;
    hi[0]=(bf16)f2.x; hi[1]=(bf16)f2.y; hi[2]=(bf16)f2.z; hi[3]=(bf16)f2.w;
    hi[4]=(bf16)f3.x; hi[5]=(bf16)f3.y; hi[6]=(bf16)f3.z; hi[7]=(bf16)f3.w;
    *(bf16x8*)(dst)     = lo;
    *(bf16x8*)(dst + 8) = hi;
}

// ---------------- scores + FUSED context partial --------------------------
// GEMM(M=131072,K=512,N=256) + tanh.v epilogue -> unnormalized e_r = exp(score)
// -> immediate GEMV over the block's own 128 enc rows (L2/L3-hot: we just
// streamed them) accumulated into ctx_acc via atomicAdd. Removes the entire
// second HBM pass over enc (268 MB).
__global__ __launch_bounds__(256, 2) void k_scores_ctx(
    const float* __restrict__ enc,    // [131072][512]
    const bf16*  __restrict__ WT,     // [256][512] (n-major)
    const float* __restrict__ dp,     // [64][256]
    const float* __restrict__ v,      // [256]
    float* __restrict__ attn_e,       // [64][2048] unnormalized e (normalized later)
    float* __restrict__ ctx_acc,      // [64][512] fp32 accumulator
    float* __restrict__ esum)         // [64]
{
    __shared__ __align__(16) bf16 As[2][128 * 40];   // 2 x 10.0 KB, padded rows
    __shared__ __align__(16) bf16 Bs[2][256 * 32];   // 2 x 16.0 KB, swizzled chunks
    __shared__ float partial[4][64];
    __shared__ float ew[128];

    const int tid  = threadIdx.x;
    const int wave = tid >> 6;
    const int lane = tid & 63;
    const int l15  = lane & 15;
    const int q    = lane >> 4;
    const int m0   = blockIdx.x * 128;
    const int b    = blockIdx.x >> 4;            // 16 blocks per batch

    const int mrow0 = (wave >> 1) * 64;
    const int ncol0 = (wave & 1) * 128;

    const f32x4 zero4 = {0.f, 0.f, 0.f, 0.f};
    f32x4 acc[4][8];
#pragma unroll
    for (int mt = 0; mt < 4; ++mt)
#pragma unroll
        for (int nt = 0; nt < 8; ++nt)
            acc[mt][nt] = zero4;

    // A staging: thread t -> row t>>1, k-half (t&1)*16 floats
    const int arow = tid >> 1;
    const int akc  = tid & 1;
    const float* ag = enc + (size_t)(m0 + arow) * 512 + akc * 16;
    const int aoff = arow * 40 + akc * 16;

    // B staging: round r -> col c = r*64 + (t>>2), chunk slot t&3
    const int bcol4 = tid >> 2;
    const int bslot = tid & 3;

    // A prefetch registers: X and Y buffers (static rotation)
    float4 xa0, xa1, xa2, xa3;   // X
    float4 ya0, ya1, ya2, ya3;   // Y

    // ---- prologue: issue A(0)->X, A(1)->Y, stage B(0); publish As[0] ----
    load_a4(ag,      xa0, xa1, xa2, xa3);
    load_a4(ag + 32, ya0, ya1, ya2, ya3);
    stage_b(WT, Bs[0], 0, bcol4, bslot, tid);
    cvt_store(&As[0][aoff], xa0, xa1, xa2, xa3);
    __syncthreads();

#pragma unroll
    for (int ks = 0; ks < 16; ++ks) {
        const int cur = ks & 1;
        const bf16* Asc = As[cur];
        const bf16* Bsc = Bs[cur];

        // ---- fragments (current buffer) ----
        bf16x8 af[4];
#pragma unroll
        for (int mt = 0; mt < 4; ++mt) {
            int row = mrow0 + mt * 16 + l15;
            af[mt] = *(const bf16x8*)(Asc + row * 40 + q * 8);
        }
        bf16x8 bfr[8];
#pragma unroll
        for (int nt = 0; nt < 8; ++nt) {
            int col = ncol0 + nt * 16 + l15;
            int p = q ^ ((col + (col >> 2)) & 3);
            bfr[nt] = *(const bf16x8*)(Bsc + col * 32 + p * 8);
        }

        // ---- issue next-tile loads BEFORE compute ----
        if (ks < 15) stage_b(WT, Bs[cur ^ 1], ks + 1, bcol4, bslot, tid);
        if (ks < 14) {
            const float* s = ag + (ks + 2) * 32;
            if ((ks & 1) == 0) load_a4(s, xa0, xa1, xa2, xa3);   // even: refill X
            else               load_a4(s, ya0, ya1, ya2, ya3);   // odd:  refill Y
        }

#pragma unroll
        for (int mt = 0; mt < 4; ++mt)
#pragma unroll
            for (int nt = 0; nt < 8; ++nt)
                acc[mt][nt] = __builtin_amdgcn_mfma_f32_16x16x32_bf16(af[mt], bfr[nt], acc[mt][nt], 0, 0, 0);

        // ---- convert + write A(ks+1) (issued two steps ago) ----
        if (ks < 15) {
            bf16* dst = &As[cur ^ 1][aoff];
            if ((ks & 1) == 0) cvt_store(dst, ya0, ya1, ya2, ya3);  // even consumes Y
            else               cvt_store(dst, xa0, xa1, xa2, xa3);  // odd  consumes X
        }
        __syncthreads();   // single barrier: publishes next buffer, retires reads
    }

    // ---- epilogue: score[row] = sum_col tanh(C + dp[col]) * v[col] ----
    float dpv[8], vv[8];
#pragma unroll
    for (int nt = 0; nt < 8; ++nt) {
        int col = ncol0 + nt * 16 + l15;
        dpv[nt] = dp[b * 256 + col];
        vv[nt]  = v[col];
    }
#pragma unroll
    for (int mt = 0; mt < 4; ++mt) {
#pragma unroll
        for (int r = 0; r < 4; ++r) {
            float s = 0.f;
#pragma unroll
            for (int nt = 0; nt < 8; ++nt)
                s += fast_tanh(acc[mt][nt][r] + dpv[nt]) * vv[nt];
            s += __shfl_xor(s, 1, 16);
            s += __shfl_xor(s, 2, 16);
            s += __shfl_xor(s, 4, 16);
            s += __shfl_xor(s, 8, 16);
            if (l15 == 0)
                partial[wave][mt * 16 + q * 4 + r] = s;
        }
    }
    __syncthreads();

    // ---- e_r = exp(score), unnormalized; stash in LDS + global attn_e ----
    if (tid < 128) {
        float s = partial[(tid >> 6) * 2][tid & 63] + partial[(tid >> 6) * 2 + 1][tid & 63];
        float e = fexp2(s * 1.4426950408889634f);   // |s| <~ 11 -> e in fp32 range
        ew[tid] = e;
        attn_e[(size_t)b * 2048 + (blockIdx.x & 15) * 128 + tid] = e;
        // per-block sum of e -> per-batch atomic (2 atomics/block)
        float es = e;
#pragma unroll
        for (int d = 1; d < 64; d <<= 1) es += __shfl_xor(es, d);
        if ((tid & 63) == 0) atomicAdd(esum + b, es);
    }
    __syncthreads();

    // ---- fused context GEMV over this block's 128 rows (L2/L3-hot) ----
    // thread t owns cols 2t, 2t+1; 8 independent float2 loads in flight.
    {
        const float* eb = enc + (size_t)m0 * 512;
        const int col = tid * 2;
        float cx = 0.f, cy = 0.f;
#pragma unroll
        for (int g = 0; g < 16; ++g) {
            float2 ev[8];
            float  wv[8];
#pragma unroll
            for (int j = 0; j < 8; ++j) {
                ev[j] = *(const float2*)(eb + (size_t)(g * 8 + j) * 512 + col);
                wv[j] = ew[g * 8 + j];
            }
#pragma unroll
            for (int j = 0; j < 8; ++j) { cx += ev[j].x * wv[j]; cy += ev[j].y * wv[j]; }
        }
        float* cp = ctx_acc + (size_t)b * 512 + col;
        atomicAdd(cp + 0, cx);
        atomicAdd(cp + 1, cy);
    }
}

// ---------------- finalize: divide attn row and ctx by esum ---------------
__global__ __launch_bounds__(256) void k_finalize(const float* __restrict__ ctx_acc,
                                                  const float* __restrict__ esum,
                                                  float* __restrict__ ctx,
                                                  float* __restrict__ attn) {
    const int b   = blockIdx.x;
    const int tid = threadIdx.x;
    const float inv = 1.0f / esum[b];

    float4* ap = (float4*)(attn + (size_t)b * 2048);
#pragma unroll
    for (int i = 0; i < 2; ++i) {
        float4 t = ap[tid + 256 * i];
        t.x *= inv; t.y *= inv; t.z *= inv; t.w *= inv;
        ap[tid + 256 * i] = t;
    }
    float2 c = *(const float2*)(ctx_acc + (size_t)b * 512 + tid * 2);
    *(float2*)(ctx + (size_t)b * 512 + tid * 2) = make_float2(c.x * inv, c.y * inv);
}

extern "C" void kernel_launch(void* const* d_in, const int* in_sizes, int n_in,
                              void* d_out, int out_size, void* d_ws, size_t ws_size,
                              hipStream_t stream) {
    const float* enc       = (const float*)d_in[0];
    const float* dec_state = (const float*)d_in[1];
    const float* W_enc     = (const float*)d_in[2];
    const float* W_dec     = (const float*)d_in[3];
    const float* v         = (const float*)d_in[4];

    float* ctx  = (float*)d_out;                 // [64,512]
    float* attn = (float*)d_out + 64 * 512;      // [64,2048] weights (e -> normalized in place)

    // workspace: WT bf16 256KB | dp fp32 64KB | ctx_acc fp32 128KB | esum 256B
    char*  ws      = (char*)d_ws;
    bf16*  WT      = (bf16*)ws;
    float* dp      = (float*)(ws + 256 * 1024);
    float* ctx_acc = (float*)(ws + 256 * 1024 + 64 * 1024);
    float* esum    = (float*)(ws + 256 * 1024 + 64 * 1024 + 128 * 1024);

    k_setup      <<<576,  256, 0, stream>>>(W_enc, dec_state, W_dec, WT, dp, ctx_acc, esum);
    k_scores_ctx <<<1024, 256, 0, stream>>>(enc, WT, dp, v, attn, ctx_acc, esum);
    k_finalize   <<<64,   256, 0, stream>>>(ctx_acc, esum, ctx, attn);
}